// Round 3
// baseline (786.861 us; speedup 1.0000x reference)
//
#include <hip/hip_runtime.h>

#define NPIX 65536

// ws layout (float offsets). KOFF planes are dead after conv -> U3/MUX/MUY overlay.
#define WS_APLANE 0                  // 3 planes
#define WS_ASUM   (3*NPIX)           // 1 plane
#define WS_KOFF   (4*NPIX)           // 10 planes (conv stage)
#define WS_U3     (4*NPIX)           // post-conv overlay
#define WS_MUX    (7*NPIX)
#define WS_MUY    (10*NPIX)
#define WS_UACC   (14*NPIX)          // 10 planes of per-kernel partial U
#define WS_KSUM   (24*NPIX)          // 10 floats (stores 1/total)
#define WS_RING   (24*NPIX+16)       // 10*130
#define WS_KRAD   (24*NPIX+1328)     // 10 ints
#define WS_TICKET (24*NPIX+1340)     // 1 int
#define WS_END    (24*NPIX+1344)

__global__ void repack(const float* __restrict__ A, float* __restrict__ ws) {
    int idx = blockIdx.x * 256 + threadIdx.x;
    float a0 = A[idx*3+0], a1 = A[idx*3+1], a2 = A[idx*3+2];
    ws[WS_APLANE + idx]          = a0;
    ws[WS_APLANE + NPIX + idx]   = a1;
    ws[WS_APLANE + 2*NPIX + idx] = a2;
    ws[WS_ASUM + idx] = a0 + a1 + a2;
}

__global__ void build_kernels(const float* __restrict__ R_, const float* __restrict__ r_,
                              const float* __restrict__ a_, const float* __restrict__ b_,
                              const float* __restrict__ w_, float* __restrict__ ws) {
    __shared__ float rs[132];
    int k = blockIdx.x >> 8;
    int i = blockIdx.x & 255;
    int j = threadIdx.x;
    if (threadIdx.x < 132) rs[threadIdx.x] = 0.0f;
    __syncthreads();
    float R = R_[0];
    float denom = (R + 15.0f) * r_[k];
    int di = i - 128, dj = j - 128;
    float D  = sqrtf((float)(di*di + dj*dj));
    float Dk = D / denom;
    float ker = 0.0f;
    #pragma unroll
    for (int t = 0; t < 3; ++t) {
        float d = Dk - a_[k*3+t];
        ker += b_[k*3+t] * expf(-((d*d) / w_[k*3+t]));
    }
    // 0.5*(tanh(-5(Dk-1))+1) == logistic(−10(Dk−1)) exactly
    float sig = 1.0f / (1.0f + expf(10.0f * (Dk - 1.0f)));
    float v = sig * ker;
    ws[WS_KOFF + k*NPIX + i*256 + j] = v;
    int adi = di < 0 ? -di : di;
    int adj = dj < 0 ? -dj : dj;
    int ring = adi > adj ? adi : adj;
    atomicAdd(&rs[ring], v);
    __syncthreads();
    if (threadIdx.x < 130) {
        float sv = rs[threadIdx.x];
        if (sv != 0.0f) atomicAdd(&ws[WS_RING + k*130 + threadIdx.x], sv);
    }
}

// One wave per kernel k: total + max ring with relative tail > 1e-6, via shuffles.
__global__ void finalize_v2(const float* __restrict__ ring,
                            float* __restrict__ kinv, int* __restrict__ krad) {
    int k = threadIdx.x >> 6;
    int lane = threadIdx.x & 63;
    const float* rs = ring + k*130;
    float v0 = rs[2*lane];
    float v1 = rs[2*lane+1];
    float v2 = (lane == 63) ? rs[128] : 0.0f;
    float pair = v0 + v1 + v2;
    float suf = pair;                      // reverse inclusive scan: suf[l]=sum_{>=l}
    #pragma unroll
    for (int off = 1; off < 64; off <<= 1) {
        float t = __shfl_down(suf, off);
        suf += (lane + off < 64) ? t : 0.0f;
    }
    float total = __shfl(suf, 0);
    float tol = 1e-6f * total;
    int best = -1;
    if (lane == 63 && (suf - v0 - v1) > tol) best = 128;
    if ((suf - v0) > tol) best = best > 2*lane+1 ? best : 2*lane+1;
    if (suf > tol)        best = best > 2*lane   ? best : 2*lane;
    #pragma unroll
    for (int off = 32; off; off >>= 1) {
        int o = __shfl_xor(best, off);
        best = o > best ? o : best;
    }
    if (lane == 0) {
        int rad = best; if (rad > 127) rad = 127; if (rad < 1) rad = 1;
        kinv[k] = 1.0f / total;
        krad[k] = rad;
    }
}

// Padded LDS index: stride-4 lane pattern -> +p/32 keeps it at free 2-way.
#define B(P) buf[(P) + ((P)>>5)]

template<int NACT>
__device__ __forceinline__ void conv_dj(const float* koff, float* __restrict__ buf,
                                        float acc[4][4], int k0, int k1, int k2, int k3,
                                        int di, int rad0, int y0) {
    int ks[4] = {k0, k1, k2, k3};
    const float* krow[4];
    #pragma unroll
    for (int kk = 0; kk < NACT; ++kk)
        krow[kk] = koff + ks[kk]*NPIX + (di+128)*256 + 128;

    #define FMAS(DJ, W0, W1, W2, W3) do {                       \
        _Pragma("unroll")                                       \
        for (int kk = 0; kk < NACT; ++kk) {                     \
            float kv = krow[kk][(DJ)];                          \
            acc[kk][0] = fmaf(kv, (W0), acc[kk][0]);            \
            acc[kk][1] = fmaf(kv, (W1), acc[kk][1]);            \
            acc[kk][2] = fmaf(kv, (W2), acc[kk][2]);            \
            acc[kk][3] = fmaf(kv, (W3), acc[kk][3]);            \
        } } while (0)

    int p = y0 + 128 + rad0;
    float a0 = B(p), a1 = B(p+1), a2 = B(p+2), a3 = B(p+3);
    int dj = -rad0;
    for (; dj + 3 <= rad0; dj += 4) {
        FMAS(dj,   a0, a1, a2, a3);
        float n1 = B(p-1);  FMAS(dj+1, n1, a0, a1, a2);
        float n2 = B(p-2);  FMAS(dj+2, n2, n1, a0, a1);
        float n3 = B(p-3);  FMAS(dj+3, n3, n2, n1, a0);
        float n4 = B(p-4);
        a0 = n4; a1 = n3; a2 = n2; a3 = n1; p -= 4;
    }
    for (; dj <= rad0; ++dj) {
        FMAS(dj, a0, a1, a2, a3);
        float nw = B(p-1);
        a3 = a2; a2 = a1; a1 = a0; a0 = nw; --p;
    }
    #undef FMAS
}

#define CSWAP(RA, RB, KA, KB) do { if ((RB) > (RA)) { int _t=(RA);(RA)=(RB);(RB)=_t; _t=(KA);(KA)=(KB);(KB)=_t; } } while (0)

// Persistent per-wave work stealing. Task = (c, row, di). Ticket order is
// row-major so consecutive tickets share a row -> register accumulation,
// one atomic flush per row-run. Kernels gated by rad_k >= |di| (sorted desc).
__global__ __launch_bounds__(256) void conv_v3(const float* __restrict__ aplanes,
                                               const float* koff,
                                               const int* __restrict__ krad,
                                               float* __restrict__ uacc,
                                               int* __restrict__ ticket) {
    __shared__ float lds[4*528];
    int wid = threadIdx.x >> 6, lane = threadIdx.x & 63;
    float* buf = &lds[wid*528];
    int y0 = lane * 4;

    // sorted (rad desc) kernel lists per channel, all in named scalars (SGPRs)
    int k00=0,k01=1,k02=2,k03=9, r00=krad[0],r01=krad[1],r02=krad[2],r03=krad[9];
    CSWAP(r00,r01,k00,k01); CSWAP(r02,r03,k02,k03);
    CSWAP(r00,r02,k00,k02); CSWAP(r01,r03,k01,k03); CSWAP(r01,r02,k01,k02);
    int k10=3,k11=4,k12=5, r10=krad[3],r11=krad[4],r12=krad[5];
    CSWAP(r10,r11,k10,k11); CSWAP(r11,r12,k11,k12); CSWAP(r10,r11,k10,k11);
    int k20=6,k21=7,k22=8, r20=krad[6],r21=krad[7],r22=krad[8];
    CSWAP(r20,r21,k20,k21); CSWAP(r21,r22,k21,k22); CSWAP(r20,r21,k20,k21);

    int W0 = 2*r00+1, W1 = 2*r10+1, W2 = 2*r20+1;
    int T0 = 256*W0, T1 = 256*W1;
    int Ttot = T0 + T1 + 256*W2;

    float acc[4][4];
    #pragma unroll
    for (int i = 0; i < 4; ++i)
        #pragma unroll
        for (int j = 0; j < 4; ++j) acc[i][j] = 0.0f;

    int curc = -1, curx = -1, curnk = 0;
    int ck0=0, ck1=0, ck2=0, ck3=0;      // current channel sorted kernels
    int cr1=0, cr2=0, cr3=0, crmax=0;    // their radii (cr0==crmax)

    while (true) {
        int t = 0;
        if (lane == 0) t = atomicAdd(ticket, 1);
        t = __shfl(t, 0);
        bool done = (t >= Ttot);
        int c = 0, tl = t;
        if (!done) {
            if (t >= T0 + T1)      { c = 2; tl = t - T0 - T1; }
            else if (t >= T0)      { c = 1; tl = t - T0; }
        }
        int Wc   = (c == 0) ? W0 : (c == 1 ? W1 : W2);
        int newx = tl / Wc;
        if (done || c != curc || newx != curx) {
            if (curc >= 0) {                       // flush previous row-run
                int ob = curx*256 + y0;
                int fk[4] = {ck0, ck1, ck2, ck3};
                for (int kk = 0; kk < curnk; ++kk) {
                    float* up = uacc + fk[kk]*NPIX + ob;
                    atomicAdd(up+0, acc[kk][0]);
                    atomicAdd(up+1, acc[kk][1]);
                    atomicAdd(up+2, acc[kk][2]);
                    atomicAdd(up+3, acc[kk][3]);
                }
                #pragma unroll
                for (int i = 0; i < 4; ++i)
                    #pragma unroll
                    for (int j = 0; j < 4; ++j) acc[i][j] = 0.0f;
            }
            if (done) return;
            curc = c; curx = newx;
            curnk = (c == 0) ? 4 : 3;
            ck0 = c==0?k00:(c==1?k10:k20);
            ck1 = c==0?k01:(c==1?k11:k21);
            ck2 = c==0?k02:(c==1?k12:k22);
            ck3 = k03;                              // only used when c==0
            crmax = c==0?r00:(c==1?r10:r20);
            cr1   = c==0?r01:(c==1?r11:r21);
            cr2   = c==0?r02:(c==1?r12:r22);
            cr3   = r03;
        }
        int di = (tl - newx*Wc) - crmax;
        // stage source row (per-wave private buffer; DS in-order within wave)
        {
            const float* arow = aplanes + c*NPIX + (((newx - di) & 255) << 8);
            #pragma unroll
            for (int tt = 0; tt < 8; ++tt) {
                int j = tt*64 + lane;
                buf[j + (j>>5)] = arow[(j - 128) & 255];
            }
        }
        int adi = di < 0 ? -di : di;
        int nact = 1;
        if (cr1 >= adi) nact = 2;
        if (nact == 2 && cr2 >= adi) nact = 3;
        if (nact == 3 && curnk == 4 && cr3 >= adi) nact = 4;
        switch (nact) {
            case 1: conv_dj<1>(koff, buf, acc, ck0, ck1, ck2, ck3, di, crmax, y0); break;
            case 2: conv_dj<2>(koff, buf, acc, ck0, ck1, ck2, ck3, di, crmax, y0); break;
            case 3: conv_dj<3>(koff, buf, acc, ck0, ck1, ck2, ck3, di, crmax, y0); break;
            default: conv_dj<4>(koff, buf, acc, ck0, ck1, ck2, ck3, di, crmax, y0); break;
        }
    }
}

__global__ void growth_k(float* __restrict__ ws, const float* __restrict__ m_,
                         const float* __restrict__ s_, const float* __restrict__ h_) {
    int idx = blockIdx.x*256 + threadIdx.x;
    const float* uacc = ws + WS_UACC;
    #pragma unroll
    for (int c = 0; c < 3; ++c) {
        int nk = (c == 0) ? 4 : 3;
        float outv = 0.0f;
        for (int kk = 0; kk < nk; ++kk) {
            int k = (kk == 3) ? 9 : c*3 + kk;
            float U = uacc[k*NPIX + idx] * ws[WS_KSUM + k];   // kinv
            float z = (U - m_[k]) / s_[k];
            outv += h_[k] * (expf(-0.5f*z*z)*2.0f - 1.0f);
        }
        ws[WS_U3 + c*NPIX + idx] = outv;
    }
}

__device__ inline void sobel_at(const float* __restrict__ p, int x, int y,
                                float& gy, float& gx) {
    float v[3][3];
    #pragma unroll
    for (int ii = -1; ii <= 1; ++ii)
        #pragma unroll
        for (int jj = -1; jj <= 1; ++jj) {
            int xx = x + ii, yy = y + jj;
            v[ii+1][jj+1] = (xx < 0 || xx > 255 || yy < 0 || yy > 255)
                            ? 0.0f : p[xx*256 + yy];
        }
    gy = (v[0][0] + 2.0f*v[0][1] + v[0][2]) - (v[2][0] + 2.0f*v[2][1] + v[2][2]);
    gx = (v[0][0] + 2.0f*v[1][0] + v[2][0]) - (v[0][2] + 2.0f*v[1][2] + v[2][2]);
}

__global__ void compute_mu(float* __restrict__ ws) {
    int x = blockIdx.x;
    int y = threadIdx.x;
    float gyA, gxA;
    sobel_at(ws + WS_ASUM, x, y, gyA, gxA);
    #pragma unroll
    for (int c = 0; c < 3; ++c) {
        float gy, gx;
        sobel_at(ws + WS_U3 + c*NPIX, x, y, gy, gx);
        float a = ws[WS_APLANE + c*NPIX + x*256 + y];
        float al = (a / 3.0f); al = al * al;
        al = fminf(fmaxf(al, 0.0f), 1.0f);
        float F0 = gy * (1.0f - al) - gyA * al;
        float F1 = gx * (1.0f - al) - gxA * al;
        float d0 = fminf(fmaxf(0.2f * F0, -4.35f), 4.35f);
        float d1 = fminf(fmaxf(0.2f * F1, -4.35f), 4.35f);
        ws[WS_MUX + c*NPIX + x*256 + y] = fminf(fmaxf((float)x + 0.5f + d0, 0.65f), 255.35f);
        ws[WS_MUY + c*NPIX + x*256 + y] = fminf(fmaxf((float)y + 0.5f + d1, 0.65f), 255.35f);
    }
}

// Block = (c, x-row). Stage 11 halo rows of A/mux/muy in LDS, then 121 taps from LDS.
__global__ __launch_bounds__(256) void rt_apply_v2(const float* __restrict__ ws,
                                                   float* __restrict__ out) {
    __shared__ float sA[11*256], sX[11*256], sY[11*256];
    int b = blockIdx.x;
    int c = b >> 8;
    int x = b & 255;
    const float* ap = ws + WS_APLANE + c*NPIX;
    const float* mx = ws + WS_MUX + c*NPIX;
    const float* my = ws + WS_MUY + c*NPIX;
    int t = threadIdx.x;
    #pragma unroll
    for (int i = 0; i < 11; ++i) {
        int src = (((x - (i - 5)) & 255) << 8) + t;   // row i holds source x-(i-5)
        sA[i*256 + t] = ap[src];
        sX[i*256 + t] = mx[src];
        sY[i*256 + t] = my[src];
    }
    __syncthreads();
    int y = t;
    float px = (float)x + 0.5f, py = (float)y + 0.5f;
    float acc = 0.0f;
    #pragma unroll
    for (int dx = -5; dx <= 5; ++dx) {
        int rb = (dx + 5) * 256;
        for (int dy = -5; dy <= 5; ++dy) {
            int sy = (y - dy) & 255;
            float a  = sA[rb + sy];
            float ax = 1.15f - fabsf(px - sX[rb + sy]);
            float ay = 1.15f - fabsf(py - sY[rb + sy]);
            ax = fminf(fmaxf(ax, 0.0f), 1.0f);
            ay = fminf(fmaxf(ay, 0.0f), 1.0f);
            acc = fmaf(a, ax * ay, acc);
        }
    }
    out[(x*256 + y)*3 + c] = acc * (1.0f / (4.0f * 0.65f * 0.65f));
}

extern "C" void kernel_launch(void* const* d_in, const int* in_sizes, int n_in,
                              void* d_out, int out_size, void* d_ws, size_t ws_size,
                              hipStream_t stream) {
    const float* A = (const float*)d_in[0];
    const float* R = (const float*)d_in[1];
    const float* r = (const float*)d_in[2];
    const float* m = (const float*)d_in[3];
    const float* s = (const float*)d_in[4];
    const float* h = (const float*)d_in[5];
    const float* a = (const float*)d_in[6];
    const float* b = (const float*)d_in[7];
    const float* w = (const float*)d_in[8];
    float* ws  = (float*)d_ws;
    float* out = (float*)d_out;

    // zero UACC + KSUM + RING + KRAD + TICKET (ws is re-poisoned before every call)
    hipMemsetAsync((char*)d_ws + (size_t)WS_UACC*sizeof(float), 0,
                   (size_t)(WS_END - WS_UACC)*sizeof(float), stream);

    repack<<<256, 256, 0, stream>>>(A, ws);
    build_kernels<<<2560, 256, 0, stream>>>(R, r, a, b, w, ws);
    finalize_v2<<<1, 640, 0, stream>>>(ws + WS_RING, ws + WS_KSUM, (int*)ws + WS_KRAD);
    conv_v3<<<2048, 256, 0, stream>>>(ws + WS_APLANE, ws + WS_KOFF,
                                      (const int*)ws + WS_KRAD, ws + WS_UACC,
                                      (int*)ws + WS_TICKET);
    growth_k<<<256, 256, 0, stream>>>(ws, m, s, h);
    compute_mu<<<256, 256, 0, stream>>>(ws);
    rt_apply_v2<<<768, 256, 0, stream>>>(ws, out);
}

// Round 4
// 215.374 us; speedup vs baseline: 3.6535x; 3.6535x over previous
//
#include <hip/hip_runtime.h>

#define NPIX 65536

// ws layout (float offsets). KOFF planes are dead after conv -> U3/MUX/MUY overlay.
#define WS_APLANE 0                  // 3 planes
#define WS_ASUM   (3*NPIX)           // 1 plane
#define WS_KOFF   (4*NPIX)           // 10 planes (conv stage)
#define WS_U3     (4*NPIX)           // post-conv overlay
#define WS_MUX    (7*NPIX)
#define WS_MUY    (10*NPIX)
#define WS_UACC   (14*NPIX)          // 10 planes of per-kernel partial U
#define WS_KSUM   (24*NPIX)          // 10 floats (stores 1/total)
#define WS_ROWS   (24*NPIX+16)       // 10*256 per-row kernel sums
#define WS_KRAD   (24*NPIX+16+2560)  // 10 ints
#define WS_END    (24*NPIX+16+2576)

#define SSEG 16   // di-range split factor for conv occupancy

__global__ void repack(const float* __restrict__ A, float* __restrict__ ws) {
    int idx = blockIdx.x * 256 + threadIdx.x;
    float a0 = A[idx*3+0], a1 = A[idx*3+1], a2 = A[idx*3+2];
    ws[WS_APLANE + idx]          = a0;
    ws[WS_APLANE + NPIX + idx]   = a1;
    ws[WS_APLANE + 2*NPIX + idx] = a2;
    ws[WS_ASUM + idx] = a0 + a1 + a2;
}

// Build Koff[k][di+128][dj+128]; per-(k,row) sum via conflict-free LDS tree
// (no atomics anywhere — the ring-atomic storm of r1-r3 is gone).
__global__ void build_kernels(const float* __restrict__ R_, const float* __restrict__ r_,
                              const float* __restrict__ a_, const float* __restrict__ b_,
                              const float* __restrict__ w_, float* __restrict__ koff,
                              float* __restrict__ rows) {
    __shared__ float red[256];
    int k = blockIdx.x >> 8;
    int i = blockIdx.x & 255;
    int j = threadIdx.x;
    float R = R_[0];
    float denom = (R + 15.0f) * r_[k];
    int di = i - 128, dj = j - 128;
    float D  = sqrtf((float)(di*di + dj*dj));
    float Dk = D / denom;
    float ker = 0.0f;
    #pragma unroll
    for (int t = 0; t < 3; ++t) {
        float d = Dk - a_[k*3+t];
        ker += b_[k*3+t] * expf(-((d*d) / w_[k*3+t]));
    }
    // 0.5*(tanh(-5(Dk-1))+1) == logistic(-10(Dk-1)) exactly
    float sig = 1.0f / (1.0f + expf(10.0f * (Dk - 1.0f)));
    float v = sig * ker;
    koff[k*NPIX + i*256 + j] = v;
    red[j] = v;
    __syncthreads();
    #pragma unroll
    for (int s = 128; s > 0; s >>= 1) {
        if (j < s) red[j] += red[j + s];
        __syncthreads();
    }
    if (j == 0) rows[k*256 + i] = red[0];
}

// One wave per kernel k. total = sum(rows); rad = max rho with 2*tail(rho) > tol
// (row-tail union bound: out-of-square mass <= 2 * row mass beyond rad).
__global__ void finalize_v3(const float* __restrict__ rows,
                            float* __restrict__ kinv, int* __restrict__ krad) {
    int k = threadIdx.x >> 6;
    int lane = threadIdx.x & 63;
    const float* rw = rows + k*256;
    // s(rho): paired row sums. rho=2*lane and 2*lane+1; lane 63 also owns rho=128.
    int r0i = 2*lane, r1i = 2*lane+1;
    float v0 = (r0i == 0) ? rw[128] : rw[128+r0i] + rw[128-r0i];
    float v1 = rw[128+r1i] + rw[128-r1i];       // r1i in 1..127
    float v2 = (lane == 63) ? rw[0] : 0.0f;     // rho=128 (di=-128 only)
    float suf = v0 + v1 + v2;                   // reverse inclusive scan
    #pragma unroll
    for (int off = 1; off < 64; off <<= 1) {
        float t = __shfl_down(suf, off);
        suf += (lane + off < 64) ? t : 0.0f;
    }
    float total = __shfl(suf, 0);
    float tol = 1e-6f * total;
    int best = -1;
    if (lane == 63 && 2.0f*(suf - v0 - v1) > tol) best = 128;
    if (2.0f*(suf - v0) > tol) best = best > r1i ? best : r1i;
    if (2.0f*suf        > tol) best = best > r0i ? best : r0i;
    #pragma unroll
    for (int off = 32; off; off >>= 1) {
        int o = __shfl_xor(best, off);
        best = o > best ? o : best;
    }
    if (lane == 0) {
        int rad = best; if (rad > 127) rad = 127; if (rad < 1) rad = 1;
        kinv[k] = 1.0f / total;
        krad[k] = rad;
    }
}

// Padded LDS index: stride-4 lane pattern stays at free 2-way aliasing.
#define B(P) buf[(P) + ((P)>>5)]

template<int NACT>
__device__ __forceinline__ void conv_dj(const float* koff, float* __restrict__ buf,
                                        float acc[4][4], int k0, int k1, int k2, int k3,
                                        int di, int rad0, int y0) {
    int ks[4] = {k0, k1, k2, k3};
    const float* krow[4];
    #pragma unroll
    for (int kk = 0; kk < NACT; ++kk)
        krow[kk] = koff + ks[kk]*NPIX + (di+128)*256 + 128;

    #define FMAS(DJ, W0, W1, W2, W3) do {                       \
        _Pragma("unroll")                                       \
        for (int kk = 0; kk < NACT; ++kk) {                     \
            float kv = krow[kk][(DJ)];                          \
            acc[kk][0] = fmaf(kv, (W0), acc[kk][0]);            \
            acc[kk][1] = fmaf(kv, (W1), acc[kk][1]);            \
            acc[kk][2] = fmaf(kv, (W2), acc[kk][2]);            \
            acc[kk][3] = fmaf(kv, (W3), acc[kk][3]);            \
        } } while (0)

    int p = y0 + 128 + rad0;
    float a0 = B(p), a1 = B(p+1), a2 = B(p+2), a3 = B(p+3);
    int dj = -rad0;
    for (; dj + 3 <= rad0; dj += 4) {
        FMAS(dj,   a0, a1, a2, a3);
        float n1 = B(p-1);  FMAS(dj+1, n1, a0, a1, a2);
        float n2 = B(p-2);  FMAS(dj+2, n2, n1, a0, a1);
        float n3 = B(p-3);  FMAS(dj+3, n3, n2, n1, a0);
        float n4 = B(p-4);
        a0 = n4; a1 = n3; a2 = n2; a3 = n1; p -= 4;
    }
    for (; dj <= rad0; ++dj) {
        FMAS(dj, a0, a1, a2, a3);
        float nw = B(p-1);
        a3 = a2; a2 = a1; a1 = a0; a0 = nw; --p;
    }
    #undef FMAS
}

#define CSWAP(RA, RB, KA, KB) do { if ((RB) > (RA)) { int _t=(RA);(RA)=(RB);(RB)=_t; _t=(KA);(KA)=(KB);(KB)=_t; } } while (0)

// Static grid: (seg, c, row-group). Each wave owns one output row; per-kernel
// di-gating via radii sorted desc; register acc, ONE atomic flush per wave.
__global__ __launch_bounds__(256) void conv_v4(const float* __restrict__ aplanes,
                                               const float* koff,
                                               const int* __restrict__ krad,
                                               float* __restrict__ uacc) {
    __shared__ float lds[4*528];
    int bid = blockIdx.x;
    int seg = bid / 192;
    int rem = bid - seg*192;
    int c   = rem >> 6;
    int rg  = rem & 63;
    int wid  = threadIdx.x >> 6;
    int lane = threadIdx.x & 63;
    int x  = rg*4 + wid;
    int y0 = lane*4;
    float* buf = &lds[wid*528];

    // channel kernel list (4th = kernel 9 for c==0, dummy rad=-1 otherwise), sorted desc
    int ka0, ka1, ka2, ka3, ra0, ra1, ra2, ra3;
    ka0 = c*3; ka1 = c*3+1; ka2 = c*3+2; ka3 = 9;
    ra0 = krad[ka0]; ra1 = krad[ka1]; ra2 = krad[ka2];
    ra3 = (c == 0) ? krad[9] : -1;
    CSWAP(ra0,ra1,ka0,ka1); CSWAP(ra2,ra3,ka2,ka3);
    CSWAP(ra0,ra2,ka0,ka2); CSWAP(ra1,ra3,ka1,ka3); CSWAP(ra1,ra2,ka1,ka2);

    int radmax = ra0;
    int W = 2*radmax + 1;
    int chunk = (W + SSEG - 1) / SSEG;
    int di_lo = -radmax + seg*chunk;
    int di_hi = di_lo + chunk;
    if (di_hi > radmax + 1) di_hi = radmax + 1;
    if (di_lo >= di_hi) return;

    const float* aplane = aplanes + c*NPIX;
    float acc[4][4];
    #pragma unroll
    for (int i = 0; i < 4; ++i)
        #pragma unroll
        for (int j = 0; j < 4; ++j) acc[i][j] = 0.0f;

    for (int di = di_lo; di < di_hi; ++di) {
        const float* arow = aplane + (((x - di) & 255) << 8);
        #pragma unroll
        for (int tt = 0; tt < 8; ++tt) {
            int j = tt*64 + lane;
            buf[j + (j>>5)] = arow[(j - 128) & 255];
        }
        // per-wave private buffer; DS pipe is in-order within a wave -> no barrier
        int adi = di < 0 ? -di : di;
        int nact = 4;
        if (ra3 < adi) nact = 3;
        if (ra2 < adi) nact = 2;
        if (ra1 < adi) nact = 1;
        switch (nact) {
            case 1: conv_dj<1>(koff, buf, acc, ka0, ka1, ka2, ka3, di, radmax, y0); break;
            case 2: conv_dj<2>(koff, buf, acc, ka0, ka1, ka2, ka3, di, radmax, y0); break;
            case 3: conv_dj<3>(koff, buf, acc, ka0, ka1, ka2, ka3, di, radmax, y0); break;
            default: conv_dj<4>(koff, buf, acc, ka0, ka1, ka2, ka3, di, radmax, y0); break;
        }
    }

    // flush kernels that were active for at least one di in this segment
    int min_adi;
    if (di_lo <= 0 && 0 < di_hi) min_adi = 0;
    else {
        int a1_ = di_lo < 0 ? -di_lo : di_lo;
        int a2_ = (di_hi-1) < 0 ? -(di_hi-1) : (di_hi-1);
        min_adi = a1_ < a2_ ? a1_ : a2_;
    }
    int ob = x*256 + y0;
    int fk[4] = {ka0, ka1, ka2, ka3};
    int fr[4] = {ra0, ra1, ra2, ra3};
    #pragma unroll
    for (int kk = 0; kk < 4; ++kk) {
        if (fr[kk] >= min_adi) {
            float* up = uacc + fk[kk]*NPIX + ob;
            atomicAdd(up+0, acc[kk][0]);
            atomicAdd(up+1, acc[kk][1]);
            atomicAdd(up+2, acc[kk][2]);
            atomicAdd(up+3, acc[kk][3]);
        }
    }
}

__global__ void growth_k(float* __restrict__ ws, const float* __restrict__ m_,
                         const float* __restrict__ s_, const float* __restrict__ h_) {
    int idx = blockIdx.x*256 + threadIdx.x;
    const float* uacc = ws + WS_UACC;
    #pragma unroll
    for (int c = 0; c < 3; ++c) {
        int nk = (c == 0) ? 4 : 3;
        float outv = 0.0f;
        for (int kk = 0; kk < nk; ++kk) {
            int k = (kk == 3) ? 9 : c*3 + kk;
            float U = uacc[k*NPIX + idx] * ws[WS_KSUM + k];   // kinv
            float z = (U - m_[k]) / s_[k];
            outv += h_[k] * (expf(-0.5f*z*z)*2.0f - 1.0f);
        }
        ws[WS_U3 + c*NPIX + idx] = outv;
    }
}

__device__ inline void sobel_at(const float* __restrict__ p, int x, int y,
                                float& gy, float& gx) {
    float v[3][3];
    #pragma unroll
    for (int ii = -1; ii <= 1; ++ii)
        #pragma unroll
        for (int jj = -1; jj <= 1; ++jj) {
            int xx = x + ii, yy = y + jj;
            v[ii+1][jj+1] = (xx < 0 || xx > 255 || yy < 0 || yy > 255)
                            ? 0.0f : p[xx*256 + yy];
        }
    gy = (v[0][0] + 2.0f*v[0][1] + v[0][2]) - (v[2][0] + 2.0f*v[2][1] + v[2][2]);
    gx = (v[0][0] + 2.0f*v[1][0] + v[2][0]) - (v[0][2] + 2.0f*v[1][2] + v[2][2]);
}

__global__ void compute_mu(float* __restrict__ ws) {
    int x = blockIdx.x;
    int y = threadIdx.x;
    float gyA, gxA;
    sobel_at(ws + WS_ASUM, x, y, gyA, gxA);
    #pragma unroll
    for (int c = 0; c < 3; ++c) {
        float gy, gx;
        sobel_at(ws + WS_U3 + c*NPIX, x, y, gy, gx);
        float a = ws[WS_APLANE + c*NPIX + x*256 + y];
        float al = (a / 3.0f); al = al * al;
        al = fminf(fmaxf(al, 0.0f), 1.0f);
        float F0 = gy * (1.0f - al) - gyA * al;
        float F1 = gx * (1.0f - al) - gxA * al;
        float d0 = fminf(fmaxf(0.2f * F0, -4.35f), 4.35f);
        float d1 = fminf(fmaxf(0.2f * F1, -4.35f), 4.35f);
        ws[WS_MUX + c*NPIX + x*256 + y] = fminf(fmaxf((float)x + 0.5f + d0, 0.65f), 255.35f);
        ws[WS_MUY + c*NPIX + x*256 + y] = fminf(fmaxf((float)y + 0.5f + d1, 0.65f), 255.35f);
    }
}

// Block = (c, x-row). Stage 11 halo rows of A/mux/muy in LDS, then 121 taps from LDS.
__global__ __launch_bounds__(256) void rt_apply_v2(const float* __restrict__ ws,
                                                   float* __restrict__ out) {
    __shared__ float sA[11*256], sX[11*256], sY[11*256];
    int b = blockIdx.x;
    int c = b >> 8;
    int x = b & 255;
    const float* ap = ws + WS_APLANE + c*NPIX;
    const float* mx = ws + WS_MUX + c*NPIX;
    const float* my = ws + WS_MUY + c*NPIX;
    int t = threadIdx.x;
    #pragma unroll
    for (int i = 0; i < 11; ++i) {
        int src = (((x - (i - 5)) & 255) << 8) + t;
        sA[i*256 + t] = ap[src];
        sX[i*256 + t] = mx[src];
        sY[i*256 + t] = my[src];
    }
    __syncthreads();
    int y = t;
    float px = (float)x + 0.5f, py = (float)y + 0.5f;
    float acc = 0.0f;
    #pragma unroll
    for (int dx = -5; dx <= 5; ++dx) {
        int rb = (dx + 5) * 256;
        for (int dy = -5; dy <= 5; ++dy) {
            int sy = (y - dy) & 255;
            float a  = sA[rb + sy];
            float ax = 1.15f - fabsf(px - sX[rb + sy]);
            float ay = 1.15f - fabsf(py - sY[rb + sy]);
            ax = fminf(fmaxf(ax, 0.0f), 1.0f);
            ay = fminf(fmaxf(ay, 0.0f), 1.0f);
            acc = fmaf(a, ax * ay, acc);
        }
    }
    out[(x*256 + y)*3 + c] = acc * (1.0f / (4.0f * 0.65f * 0.65f));
}

extern "C" void kernel_launch(void* const* d_in, const int* in_sizes, int n_in,
                              void* d_out, int out_size, void* d_ws, size_t ws_size,
                              hipStream_t stream) {
    const float* A = (const float*)d_in[0];
    const float* R = (const float*)d_in[1];
    const float* r = (const float*)d_in[2];
    const float* m = (const float*)d_in[3];
    const float* s = (const float*)d_in[4];
    const float* h = (const float*)d_in[5];
    const float* a = (const float*)d_in[6];
    const float* b = (const float*)d_in[7];
    const float* w = (const float*)d_in[8];
    float* ws  = (float*)d_ws;
    float* out = (float*)d_out;

    // zero only UACC (KSUM/ROWS/KRAD are plain stores now)
    hipMemsetAsync((char*)d_ws + (size_t)WS_UACC*sizeof(float), 0,
                   (size_t)(10*NPIX)*sizeof(float), stream);

    repack<<<256, 256, 0, stream>>>(A, ws);
    build_kernels<<<2560, 256, 0, stream>>>(R, r, a, b, w, ws + WS_KOFF, ws + WS_ROWS);
    finalize_v3<<<1, 640, 0, stream>>>(ws + WS_ROWS, ws + WS_KSUM, (int*)ws + WS_KRAD);
    conv_v4<<<SSEG*192, 256, 0, stream>>>(ws + WS_APLANE, ws + WS_KOFF,
                                          (const int*)ws + WS_KRAD, ws + WS_UACC);
    growth_k<<<256, 256, 0, stream>>>(ws, m, s, h);
    compute_mu<<<256, 256, 0, stream>>>(ws);
    rt_apply_v2<<<768, 256, 0, stream>>>(ws, out);
}

// Round 5
// 203.381 us; speedup vs baseline: 3.8689x; 1.0590x over previous
//
#include <hip/hip_runtime.h>

#define NPIX 65536

// ws layout (float offsets). KOFF planes are dead after conv -> MUX/MUY overlay.
#define WS_APLANE 0                  // 3 planes
#define WS_ASUM   (3*NPIX)           // 1 plane
#define WS_KOFF   (4*NPIX)           // 10 planes (conv stage)
#define WS_MUX    (4*NPIX)           // post-conv overlay (3 planes)
#define WS_MUY    (7*NPIX)           // 3 planes
#define WS_UACC   (14*NPIX)          // 10 planes of per-kernel partial U
#define WS_ROWS   (24*NPIX)          // 10*256 per-row kernel sums
#define WS_END    (24*NPIX+2560)

#define SSEG 16   // di-range split factor for conv occupancy

// ---------------- fused prep: repack + zero UACC + build kernels ----------------
__global__ void k_prep(const float* __restrict__ A,
                       const float* __restrict__ R_, const float* __restrict__ r_,
                       const float* __restrict__ a_, const float* __restrict__ b_,
                       const float* __restrict__ w_, float* __restrict__ ws) {
    int bid = blockIdx.x;
    int t = threadIdx.x;
    if (bid < 256) {                       // repack
        int idx = bid * 256 + t;
        float a0 = A[idx*3+0], a1 = A[idx*3+1], a2 = A[idx*3+2];
        ws[WS_APLANE + idx]          = a0;
        ws[WS_APLANE + NPIX + idx]   = a1;
        ws[WS_APLANE + 2*NPIX + idx] = a2;
        ws[WS_ASUM + idx] = a0 + a1 + a2;
        return;
    }
    if (bid < 576) {                       // zero UACC (10 planes)
        int base = WS_UACC + (bid - 256) * 2048 + t;
        #pragma unroll
        for (int i = 0; i < 8; ++i) ws[base + i*256] = 0.0f;
        return;
    }
    // build kernel planes + per-(k,row) sums via conflict-free LDS tree
    __shared__ float red[256];
    int bk = bid - 576;
    int k = bk >> 8;
    int i = bk & 255;
    float R = R_[0];
    float denom = (R + 15.0f) * r_[k];
    int di = i - 128, dj = t - 128;
    float D  = sqrtf((float)(di*di + dj*dj));
    float Dk = D / denom;
    float ker = 0.0f;
    #pragma unroll
    for (int tt = 0; tt < 3; ++tt) {
        float d = Dk - a_[k*3+tt];
        ker += b_[k*3+tt] * expf(-((d*d) / w_[k*3+tt]));
    }
    // 0.5*(tanh(-5(Dk-1))+1) == logistic(-10(Dk-1)) exactly
    float sig = 1.0f / (1.0f + expf(10.0f * (Dk - 1.0f)));
    float v = sig * ker;
    ws[WS_KOFF + k*NPIX + i*256 + t] = v;
    red[t] = v;
    __syncthreads();
    #pragma unroll
    for (int s = 128; s > 0; s >>= 1) {
        if (t < s) red[t] += red[t + s];
        __syncthreads();
    }
    if (t == 0) ws[WS_ROWS + k*256 + i] = red[0];
}

// Per-wave radius scan (all lanes return rad). rad = max rho with 2*tail(rho) > tol.
__device__ __forceinline__ int wave_rad(const float* __restrict__ rw, int lane) {
    int r0i = 2*lane, r1i = 2*lane+1;
    float v0 = (r0i == 0) ? rw[128] : rw[128+r0i] + rw[128-r0i];
    float v1 = rw[128+r1i] + rw[128-r1i];
    float v2 = (lane == 63) ? rw[0] : 0.0f;
    float suf = v0 + v1 + v2;                   // reverse inclusive scan
    #pragma unroll
    for (int off = 1; off < 64; off <<= 1) {
        float tv = __shfl_down(suf, off);
        suf += (lane + off < 64) ? tv : 0.0f;
    }
    float total = __shfl(suf, 0);
    float tol = 1e-6f * total;
    int best = -1;
    if (lane == 63 && 2.0f*(suf - v0 - v1) > tol) best = 128;
    if (2.0f*(suf - v0) > tol) best = best > r1i ? best : r1i;
    if (2.0f*suf        > tol) best = best > r0i ? best : r0i;
    #pragma unroll
    for (int off = 32; off; off >>= 1) {
        int o = __shfl_xor(best, off);
        best = o > best ? o : best;
    }
    if (best > 127) best = 127;
    if (best < 1)   best = 1;
    return best;
}

// ring-row read: col (P mod 256), padded (free-2-way aliasing pattern)
#define RD(P) rb[(((P)&255)) + ((((P)&255))>>5)]

template<int NACT>
__device__ __forceinline__ void conv_dj5(const float kb[4][264], const float* __restrict__ rb,
                                         float acc[4][4], int radmax, int y0) {
    int p = y0 + radmax;
    float a0 = RD(p), a1 = RD(p+1), a2 = RD(p+2), a3 = RD(p+3);
    int dj = -radmax;
    for (; dj + 3 <= radmax; dj += 4) {
        float4 kv[4];
        #pragma unroll
        for (int kk = 0; kk < NACT; ++kk)
            kv[kk] = *(const float4*)&kb[kk][dj + radmax];
        float n1 = RD(p-1), n2 = RD(p-2), n3 = RD(p-3), n4 = RD(p-4);
        #pragma unroll
        for (int kk = 0; kk < NACT; ++kk) {      // sub-step 0: (a0,a1,a2,a3)
            acc[kk][0] = fmaf(kv[kk].x, a0, acc[kk][0]);
            acc[kk][1] = fmaf(kv[kk].x, a1, acc[kk][1]);
            acc[kk][2] = fmaf(kv[kk].x, a2, acc[kk][2]);
            acc[kk][3] = fmaf(kv[kk].x, a3, acc[kk][3]);
        }
        #pragma unroll
        for (int kk = 0; kk < NACT; ++kk) {      // sub-step 1: (n1,a0,a1,a2)
            acc[kk][0] = fmaf(kv[kk].y, n1, acc[kk][0]);
            acc[kk][1] = fmaf(kv[kk].y, a0, acc[kk][1]);
            acc[kk][2] = fmaf(kv[kk].y, a1, acc[kk][2]);
            acc[kk][3] = fmaf(kv[kk].y, a2, acc[kk][3]);
        }
        #pragma unroll
        for (int kk = 0; kk < NACT; ++kk) {      // sub-step 2: (n2,n1,a0,a1)
            acc[kk][0] = fmaf(kv[kk].z, n2, acc[kk][0]);
            acc[kk][1] = fmaf(kv[kk].z, n1, acc[kk][1]);
            acc[kk][2] = fmaf(kv[kk].z, a0, acc[kk][2]);
            acc[kk][3] = fmaf(kv[kk].z, a1, acc[kk][3]);
        }
        #pragma unroll
        for (int kk = 0; kk < NACT; ++kk) {      // sub-step 3: (n3,n2,n1,a0)
            acc[kk][0] = fmaf(kv[kk].w, n3, acc[kk][0]);
            acc[kk][1] = fmaf(kv[kk].w, n2, acc[kk][1]);
            acc[kk][2] = fmaf(kv[kk].w, n1, acc[kk][2]);
            acc[kk][3] = fmaf(kv[kk].w, a0, acc[kk][3]);
        }
        a0 = n4; a1 = n3; a2 = n2; a3 = n1; p -= 4;
    }
    for (; dj <= radmax; ++dj) {
        #pragma unroll
        for (int kk = 0; kk < NACT; ++kk) {
            float kv = kb[kk][dj + radmax];
            acc[kk][0] = fmaf(kv, a0, acc[kk][0]);
            acc[kk][1] = fmaf(kv, a1, acc[kk][1]);
            acc[kk][2] = fmaf(kv, a2, acc[kk][2]);
            acc[kk][3] = fmaf(kv, a3, acc[kk][3]);
        }
        float nw = RD(p-1);
        a3 = a2; a2 = a1; a1 = a0; a0 = nw; --p;
    }
}

#define CSWAP(RA, RB, KA, KB) do { if ((RB) > (RA)) { int _t=(RA);(RA)=(RB);(RB)=_t; _t=(KA);(KA)=(KB);(KB)=_t; } } while (0)

// Static grid (seg, c, rowgroup). Block-shared A-row ring (1 new row/di) +
// double-buffered LDS kernel rows (kv via ds_read_b128, no global tap loads).
__global__ __launch_bounds__(256) void conv_v5(const float* __restrict__ aplanes,
                                               const float* __restrict__ koff,
                                               const float* __restrict__ rows,
                                               float* __restrict__ uacc) {
    __shared__ __align__(16) float ring[8][264];
    __shared__ __align__(16) float kbuf[2][4][264];
    __shared__ int srad[4];
    int bid = blockIdx.x;
    int seg = bid / 192;
    int rem = bid - seg*192;
    int c   = rem >> 6;
    int rg  = rem & 63;
    int wid  = threadIdx.x >> 6;
    int lane = threadIdx.x & 63;
    int t = threadIdx.x;
    int x0 = rg*4;
    int x  = x0 + wid;
    int y0 = lane*4;

    // per-block radii scan: wave w computes kernel (w<3 ? c*3+w : 9)
    {
        int kw = (wid < 3) ? c*3 + wid : 9;
        int radw = wave_rad(rows + kw*256, lane);
        if (lane == 0) srad[wid] = radw;
    }
    __syncthreads();
    int ka0 = c*3, ka1 = c*3+1, ka2 = c*3+2, ka3 = 9;
    int ra0 = srad[0], ra1 = srad[1], ra2 = srad[2];
    int ra3 = (c == 0) ? srad[3] : -1;
    CSWAP(ra0,ra1,ka0,ka1); CSWAP(ra2,ra3,ka2,ka3);
    CSWAP(ra0,ra2,ka0,ka2); CSWAP(ra1,ra3,ka1,ka3); CSWAP(ra1,ra2,ka1,ka2);

    int radmax = ra0;
    int W = 2*radmax + 1;
    int chunk = (W + SSEG - 1) / SSEG;
    int di_lo = -radmax + seg*chunk;
    int di_hi = di_lo + chunk;
    if (di_hi > radmax + 1) di_hi = radmax + 1;
    if (di_lo >= di_hi) return;

    const float* aplane = aplanes + c*NPIX;
    int fk[4] = {ka0, ka1, ka2, ka3};

    // init ring: rows x0..x0+3 - di_lo (wave wid stages its row)
    {
        int s = (x0 + wid - di_lo) & 255;
        float* sl = ring[s & 7];
        const float* ar = aplane + s*256;
        #pragma unroll
        for (int i = 0; i < 4; ++i) {
            int col = i*64 + lane;
            sl[col + (col>>5)] = ar[col];
        }
    }

    float acc[4][4];
    #pragma unroll
    for (int i = 0; i < 4; ++i)
        #pragma unroll
        for (int j = 0; j < 4; ++j) acc[i][j] = 0.0f;

    for (int di = di_lo; di < di_hi; ++di) {
        int pb = (di - di_lo) & 1;
        int adi = di < 0 ? -di : di;
        int nact = 4;
        if (ra3 < adi) nact = 3;
        if (ra2 < adi) nact = 2;
        if (ra1 < adi) nact = 1;
        // stage kernel rows for this di (width W, cols 128-radmax .. 128+radmax)
        for (int kk = 0; kk < nact; ++kk) {
            if (t < W)
                kbuf[pb][kk][t] = koff[fk[kk]*NPIX + (di+128)*256 + (128 - radmax) + t];
        }
        // stage the one new A row (rows for di: x0-di .. x0+3-di; new = x0-di)
        if (di > di_lo) {
            int srow = (x0 - di) & 255;
            ring[srow & 7][t + (t>>5)] = aplane[srow*256 + t];
        }
        __syncthreads();
        // safe without a trailing barrier: next iter writes kbuf[1-pb] and an
        // unused ring slot ((x0-di-1)&7 not among the 4 in-use slots)
        const float* rb = ring[((x - di) & 255) & 7];
        switch (nact) {
            case 1: conv_dj5<1>(kbuf[pb], rb, acc, radmax, y0); break;
            case 2: conv_dj5<2>(kbuf[pb], rb, acc, radmax, y0); break;
            case 3: conv_dj5<3>(kbuf[pb], rb, acc, radmax, y0); break;
            default: conv_dj5<4>(kbuf[pb], rb, acc, radmax, y0); break;
        }
    }

    // flush kernels active for at least one di in this segment
    int min_adi;
    if (di_lo <= 0 && 0 < di_hi) min_adi = 0;
    else {
        int a1_ = di_lo < 0 ? -di_lo : di_lo;
        int a2_ = (di_hi-1) < 0 ? -(di_hi-1) : (di_hi-1);
        min_adi = a1_ < a2_ ? a1_ : a2_;
    }
    int ob = x*256 + y0;
    int fr[4] = {ra0, ra1, ra2, ra3};
    #pragma unroll
    for (int kk = 0; kk < 4; ++kk) {
        if (fr[kk] >= min_adi) {
            float* up = uacc + fk[kk]*NPIX + ob;
            atomicAdd(up+0, acc[kk][0]);
            atomicAdd(up+1, acc[kk][1]);
            atomicAdd(up+2, acc[kk][2]);
            atomicAdd(up+3, acc[kk][3]);
        }
    }
}

__device__ inline void sobel_at(const float* __restrict__ p, int x, int y,
                                float& gy, float& gx) {
    float v[3][3];
    #pragma unroll
    for (int ii = -1; ii <= 1; ++ii)
        #pragma unroll
        for (int jj = -1; jj <= 1; ++jj) {
            int xx = x + ii, yy = y + jj;
            v[ii+1][jj+1] = (xx < 0 || xx > 255 || yy < 0 || yy > 255)
                            ? 0.0f : p[xx*256 + yy];
        }
    gy = (v[0][0] + 2.0f*v[0][1] + v[0][2]) - (v[2][0] + 2.0f*v[2][1] + v[2][2]);
    gx = (v[0][0] + 2.0f*v[1][0] + v[2][0]) - (v[0][2] + 2.0f*v[1][2] + v[2][2]);
}

// Fused kinv + growth (1-row halo recompute) + sobel + mu. Block = (c, x-row).
__global__ __launch_bounds__(256) void growth_mu(float* __restrict__ ws,
                                                 const float* __restrict__ m_,
                                                 const float* __restrict__ s_,
                                                 const float* __restrict__ h_) {
    __shared__ float Ush[3][256];
    __shared__ float kinv[4];
    int b = blockIdx.x;
    int c = b >> 8;
    int x = b & 255;
    int t = threadIdx.x, wid = t >> 6, lane = t & 63;
    int nk = (c == 0) ? 4 : 3;
    // kinv for this channel's kernels: wave w handles kernel list[w]
    if (wid < nk) {
        int k = (wid == 3) ? 9 : c*3 + wid;
        const float* rw = ws + WS_ROWS + k*256;
        float v = rw[lane] + rw[64+lane] + rw[128+lane] + rw[192+lane];
        #pragma unroll
        for (int off = 32; off; off >>= 1) v += __shfl_xor(v, off);
        if (lane == 0) kinv[wid] = 1.0f / v;
    }
    __syncthreads();
    // growth on rows x-1..x+1 (recompute halo)
    const float* uacc = ws + WS_UACC;
    for (int rr = 0; rr < 3; ++rr) {
        int xr = x - 1 + rr;
        float outv = 0.0f;
        if (xr >= 0 && xr <= 255) {
            int idx = xr*256 + t;
            for (int kk = 0; kk < nk; ++kk) {
                int k = (kk == 3) ? 9 : c*3 + kk;
                float U = uacc[k*NPIX + idx] * kinv[kk];
                float z = (U - m_[k]) / s_[k];
                outv += h_[k] * (expf(-0.5f*z*z)*2.0f - 1.0f);
            }
        }
        Ush[rr][t] = outv;
    }
    __syncthreads();
    int y = t;
    float gyA, gxA;
    sobel_at(ws + WS_ASUM, x, y, gyA, gxA);
    float v[3][3];
    #pragma unroll
    for (int ii = -1; ii <= 1; ++ii)
        #pragma unroll
        for (int jj = -1; jj <= 1; ++jj) {
            int xx = x + ii, yy = y + jj;
            v[ii+1][jj+1] = (xx < 0 || xx > 255 || yy < 0 || yy > 255)
                            ? 0.0f : Ush[ii+1][yy];
        }
    float gy = (v[0][0] + 2.0f*v[0][1] + v[0][2]) - (v[2][0] + 2.0f*v[2][1] + v[2][2]);
    float gx = (v[0][0] + 2.0f*v[1][0] + v[2][0]) - (v[0][2] + 2.0f*v[1][2] + v[2][2]);
    float a = ws[WS_APLANE + c*NPIX + x*256 + y];
    float al = (a / 3.0f); al = al * al;
    al = fminf(fmaxf(al, 0.0f), 1.0f);
    float F0 = gy * (1.0f - al) - gyA * al;
    float F1 = gx * (1.0f - al) - gxA * al;
    float d0 = fminf(fmaxf(0.2f * F0, -4.35f), 4.35f);
    float d1 = fminf(fmaxf(0.2f * F1, -4.35f), 4.35f);
    ws[WS_MUX + c*NPIX + x*256 + y] = fminf(fmaxf((float)x + 0.5f + d0, 0.65f), 255.35f);
    ws[WS_MUY + c*NPIX + x*256 + y] = fminf(fmaxf((float)y + 0.5f + d1, 0.65f), 255.35f);
}

// Block = (c, x-row). Stage 11 halo rows of A/mux/muy in LDS, then 121 taps from LDS.
__global__ __launch_bounds__(256) void rt_apply_v2(const float* __restrict__ ws,
                                                   float* __restrict__ out) {
    __shared__ float sA[11*256], sX[11*256], sY[11*256];
    int b = blockIdx.x;
    int c = b >> 8;
    int x = b & 255;
    const float* ap = ws + WS_APLANE + c*NPIX;
    const float* mx = ws + WS_MUX + c*NPIX;
    const float* my = ws + WS_MUY + c*NPIX;
    int t = threadIdx.x;
    #pragma unroll
    for (int i = 0; i < 11; ++i) {
        int src = (((x - (i - 5)) & 255) << 8) + t;
        sA[i*256 + t] = ap[src];
        sX[i*256 + t] = mx[src];
        sY[i*256 + t] = my[src];
    }
    __syncthreads();
    int y = t;
    float px = (float)x + 0.5f, py = (float)y + 0.5f;
    float acc = 0.0f;
    #pragma unroll
    for (int dx = -5; dx <= 5; ++dx) {
        int rb = (dx + 5) * 256;
        for (int dy = -5; dy <= 5; ++dy) {
            int sy = (y - dy) & 255;
            float a  = sA[rb + sy];
            float ax = 1.15f - fabsf(px - sX[rb + sy]);
            float ay = 1.15f - fabsf(py - sY[rb + sy]);
            ax = fminf(fmaxf(ax, 0.0f), 1.0f);
            ay = fminf(fmaxf(ay, 0.0f), 1.0f);
            acc = fmaf(a, ax * ay, acc);
        }
    }
    out[(x*256 + y)*3 + c] = acc * (1.0f / (4.0f * 0.65f * 0.65f));
}

extern "C" void kernel_launch(void* const* d_in, const int* in_sizes, int n_in,
                              void* d_out, int out_size, void* d_ws, size_t ws_size,
                              hipStream_t stream) {
    const float* A = (const float*)d_in[0];
    const float* R = (const float*)d_in[1];
    const float* r = (const float*)d_in[2];
    const float* m = (const float*)d_in[3];
    const float* s = (const float*)d_in[4];
    const float* h = (const float*)d_in[5];
    const float* a = (const float*)d_in[6];
    const float* b = (const float*)d_in[7];
    const float* w = (const float*)d_in[8];
    float* ws  = (float*)d_ws;
    float* out = (float*)d_out;

    k_prep<<<256 + 320 + 2560, 256, 0, stream>>>(A, R, r, a, b, w, ws);
    conv_v5<<<SSEG*192, 256, 0, stream>>>(ws + WS_APLANE, ws + WS_KOFF,
                                          ws + WS_ROWS, ws + WS_UACC);
    growth_mu<<<768, 256, 0, stream>>>(ws, m, s, h);
    rt_apply_v2<<<768, 256, 0, stream>>>(ws, out);
}

// Round 6
// 125.254 us; speedup vs baseline: 6.2821x; 1.6237x over previous
//
#include <hip/hip_runtime.h>

#define NPIX 65536

// ws layout (float offsets)
#define WS_APLANE 0                  // 3 planes
#define WS_ASUM   (3*NPIX)           // 1 plane
#define WS_KOFF   (4*NPIX)           // 10 wrapped kernel planes (dead after fft pass1)
#define WS_MUX    (4*NPIX)           // overlay (post-FFT)
#define WS_MUY    (7*NPIX)           // overlay
#define WS_UACC   (14*NPIX)          // 10 U planes (written by ifft cols)
#define WS_ROWS   (24*NPIX)          // 10*256 per-row kernel sums (for kinv)
#define WS_X1RE   (25*NPIX)          // 13 planes (pass1 out; reused as pass3 out, 10)
#define WS_X1IM   (38*NPIX)          // 13
#define WS_X2RE   (51*NPIX)          // 13 planes (pass2 out: the "hat"s)
#define WS_X2IM   (64*NPIX)          // 13
#define WS_END    (77*NPIX)          // ~20.2 MB

// ---------------- prep: repack + build wrapped kernels ----------------
__global__ void k_prep(const float* __restrict__ A,
                       const float* __restrict__ R_, const float* __restrict__ r_,
                       const float* __restrict__ a_, const float* __restrict__ b_,
                       const float* __restrict__ w_, float* __restrict__ ws) {
    int bid = blockIdx.x;
    int t = threadIdx.x;
    if (bid < 256) {                       // repack
        int idx = bid * 256 + t;
        float a0 = A[idx*3+0], a1 = A[idx*3+1], a2 = A[idx*3+2];
        ws[WS_APLANE + idx]          = a0;
        ws[WS_APLANE + NPIX + idx]   = a1;
        ws[WS_APLANE + 2*NPIX + idx] = a2;
        ws[WS_ASUM + idx] = a0 + a1 + a2;
        return;
    }
    // build kernel planes in FFT (wrapped) layout + per-(k,row) sums
    __shared__ float red[256];
    int bk = bid - 256;
    int k = bk >> 8;
    int i = bk & 255;
    float R = R_[0];
    float denom = (R + 15.0f) * r_[k];
    int di = i - 128, dj = t - 128;
    float D  = sqrtf((float)(di*di + dj*dj));
    float Dk = D / denom;
    float ker = 0.0f;
    #pragma unroll
    for (int tt = 0; tt < 3; ++tt) {
        float d = Dk - a_[k*3+tt];
        ker += b_[k*3+tt] * expf(-((d*d) / w_[k*3+tt]));
    }
    // 0.5*(tanh(-5(Dk-1))+1) == logistic(-10(Dk-1)) exactly
    float sig = 1.0f / (1.0f + expf(10.0f * (Dk - 1.0f)));
    float v = sig * ker;
    int iw = (i + 128) & 255;   // wrapped: di at index di&255  (== fftshift of centered plane)
    int jw = (t + 128) & 255;
    ws[WS_KOFF + k*NPIX + iw*256 + jw] = v;
    red[t] = v;
    __syncthreads();
    #pragma unroll
    for (int s = 128; s > 0; s >>= 1) {
        if (t < s) red[t] += red[t + s];
        __syncthreads();
    }
    if (t == 0) ws[WS_ROWS + k*256 + i] = red[0];
}

// ---------------- FFT machinery ----------------
// 256-pt radix-2 DIT on per-wave LDS re/im arrays (input already bit-reversed).
// Intra-wave only -> no barriers (DS pipe is in-order within a wave).
__device__ __forceinline__ void fft256_core(float* __restrict__ re, float* __restrict__ im,
                                            const float* __restrict__ twr,
                                            const float* __restrict__ twi, int lane) {
    #pragma unroll
    for (int s = 1; s <= 8; ++s) {
        int h = 1 << (s - 1);
        #pragma unroll
        for (int b = 0; b < 2; ++b) {
            int idx = b*64 + lane;
            int pos = idx & (h - 1);
            int g   = idx >> (s - 1);
            int i0 = (g << s) + pos;
            int i1 = i0 + h;
            int tj = pos << (8 - s);
            float wr = twr[tj], wi = twi[tj];
            float xr = re[i1], xi = im[i1];
            float br = fmaf(xr, wr, -xi*wi);
            float bi = fmaf(xr, wi,  xi*wr);
            float ar = re[i0], ai = im[i0];
            re[i0] = ar + br; im[i0] = ai + bi;
            re[i1] = ar - br; im[i1] = ai - bi;
        }
    }
}

__device__ __forceinline__ void build_tw(float* twr, float* twi, int t, float sgn) {
    if (t < 128) {
        float ang = (float)t * 0.0245436930f;   // 2*pi/256
        twr[t] = cosf(ang);
        twi[t] = sgn * sinf(ang);               // -1 forward, +1 inverse
    }
}

// transposed float4 gather-store: thread t emits (line lb..lb+3) of freq-bin t
__device__ __forceinline__ void store_t4(float* __restrict__ dst, const float* __restrict__ buf,
                                         int off, int t, int lb) {
    float4 v;
    v.x = buf[0*512 + off + t];
    v.y = buf[1*512 + off + t];
    v.z = buf[2*512 + off + t];
    v.w = buf[3*512 + off + t];
    *(float4*)&dst[t*256 + lb] = v;
}

// pass 1: forward FFT along rows of 13 REAL planes (A0..A2, K0..K9) -> X1 (transposed)
__global__ __launch_bounds__(256) void fft_fwd_real(float* __restrict__ ws) {
    __shared__ float buf[4*512];
    __shared__ float twr[128], twi[128];
    int p  = blockIdx.x >> 6;
    int lb = (blockIdx.x & 63) * 4;
    int wid = threadIdx.x >> 6, lane = threadIdx.x & 63;
    int t = threadIdx.x;
    build_tw(twr, twi, t, -1.0f);
    const float* src = ws + ((p < 3) ? (WS_APLANE + p*NPIX) : (WS_KOFF + (p-3)*NPIX));
    float* re = &buf[wid*512];
    float* im = re + 256;
    const float* row = src + (lb + wid)*256;
    #pragma unroll
    for (int e = 0; e < 4; ++e) {
        int idx = e*64 + lane;
        int dst = __brev(idx) >> 24;
        re[dst] = row[idx];
        im[dst] = 0.0f;
    }
    __syncthreads();
    fft256_core(re, im, twr, twi, lane);
    __syncthreads();
    store_t4(ws + WS_X1RE + p*NPIX, buf, 0,   t, lb);
    store_t4(ws + WS_X1IM + p*NPIX, buf, 256, t, lb);
}

// pass 2: forward FFT along rows of X1 (original cols) -> X2 = hats (natural orientation)
__global__ __launch_bounds__(256) void fft_fwd_cplx(float* __restrict__ ws) {
    __shared__ float buf[4*512];
    __shared__ float twr[128], twi[128];
    int p  = blockIdx.x >> 6;
    int lb = (blockIdx.x & 63) * 4;
    int wid = threadIdx.x >> 6, lane = threadIdx.x & 63;
    int t = threadIdx.x;
    build_tw(twr, twi, t, -1.0f);
    float* re = &buf[wid*512];
    float* im = re + 256;
    const float* rr = ws + WS_X1RE + p*NPIX + (lb + wid)*256;
    const float* ri = ws + WS_X1IM + p*NPIX + (lb + wid)*256;
    #pragma unroll
    for (int e = 0; e < 4; ++e) {
        int idx = e*64 + lane;
        int dst = __brev(idx) >> 24;
        re[dst] = rr[idx];
        im[dst] = ri[idx];
    }
    __syncthreads();
    fft256_core(re, im, twr, twi, lane);
    __syncthreads();
    store_t4(ws + WS_X2RE + p*NPIX, buf, 0,   t, lb);
    store_t4(ws + WS_X2IM + p*NPIX, buf, 256, t, lb);
}

__constant__ int C0K[10] = {0,0,0,1,1,1,2,2,2,0};

// pass 3: Uhat_k = Ahat_{C0[k]} * Khat_k, inverse FFT along rows -> X1 planes 0..9 (transposed)
__global__ __launch_bounds__(256) void ifft_mul(float* __restrict__ ws) {
    __shared__ float buf[4*512];
    __shared__ float twr[128], twi[128];
    int k  = blockIdx.x >> 6;
    int lb = (blockIdx.x & 63) * 4;
    int wid = threadIdx.x >> 6, lane = threadIdx.x & 63;
    int t = threadIdx.x;
    build_tw(twr, twi, t, 1.0f);
    int c = (k < 9) ? (k / 3) : 0;
    int rowoff = (lb + wid)*256;
    const float* arp = ws + WS_X2RE + c*NPIX + rowoff;
    const float* aip = ws + WS_X2IM + c*NPIX + rowoff;
    const float* krp = ws + WS_X2RE + (3+k)*NPIX + rowoff;
    const float* kip = ws + WS_X2IM + (3+k)*NPIX + rowoff;
    float* re = &buf[wid*512];
    float* im = re + 256;
    #pragma unroll
    for (int e = 0; e < 4; ++e) {
        int idx = e*64 + lane;
        int dst = __brev(idx) >> 24;
        float ar = arp[idx], ai = aip[idx];
        float kr = krp[idx], ki = kip[idx];
        re[dst] = ar*kr - ai*ki;
        im[dst] = ar*ki + ai*kr;
    }
    __syncthreads();
    fft256_core(re, im, twr, twi, lane);
    __syncthreads();
    store_t4(ws + WS_X1RE + k*NPIX, buf, 0,   t, lb);
    store_t4(ws + WS_X1IM + k*NPIX, buf, 256, t, lb);
}

// pass 4: inverse FFT along rows of X1 (original cols), real part / 65536 -> UACC planes
__global__ __launch_bounds__(256) void ifft_real(float* __restrict__ ws) {
    __shared__ float buf[4*512];
    __shared__ float twr[128], twi[128];
    int k  = blockIdx.x >> 6;
    int lb = (blockIdx.x & 63) * 4;
    int wid = threadIdx.x >> 6, lane = threadIdx.x & 63;
    int t = threadIdx.x;
    build_tw(twr, twi, t, 1.0f);
    float* re = &buf[wid*512];
    float* im = re + 256;
    const float* rr = ws + WS_X1RE + k*NPIX + (lb + wid)*256;
    const float* ri = ws + WS_X1IM + k*NPIX + (lb + wid)*256;
    #pragma unroll
    for (int e = 0; e < 4; ++e) {
        int idx = e*64 + lane;
        int dst = __brev(idx) >> 24;
        re[dst] = rr[idx];
        im[dst] = ri[idx];
    }
    __syncthreads();
    fft256_core(re, im, twr, twi, lane);
    __syncthreads();
    const float sc = 1.0f / 65536.0f;
    float4 v;
    v.x = buf[0*512 + t] * sc;
    v.y = buf[1*512 + t] * sc;
    v.z = buf[2*512 + t] * sc;
    v.w = buf[3*512 + t] * sc;
    *(float4*)&ws[WS_UACC + k*NPIX + t*256 + lb] = v;
}

// ---------------- post stages (unchanged, proven) ----------------
__device__ inline void sobel_at(const float* __restrict__ p, int x, int y,
                                float& gy, float& gx) {
    float v[3][3];
    #pragma unroll
    for (int ii = -1; ii <= 1; ++ii)
        #pragma unroll
        for (int jj = -1; jj <= 1; ++jj) {
            int xx = x + ii, yy = y + jj;
            v[ii+1][jj+1] = (xx < 0 || xx > 255 || yy < 0 || yy > 255)
                            ? 0.0f : p[xx*256 + yy];
        }
    gy = (v[0][0] + 2.0f*v[0][1] + v[0][2]) - (v[2][0] + 2.0f*v[2][1] + v[2][2]);
    gx = (v[0][0] + 2.0f*v[1][0] + v[2][0]) - (v[0][2] + 2.0f*v[1][2] + v[2][2]);
}

__global__ __launch_bounds__(256) void growth_mu(float* __restrict__ ws,
                                                 const float* __restrict__ m_,
                                                 const float* __restrict__ s_,
                                                 const float* __restrict__ h_) {
    __shared__ float Ush[3][256];
    __shared__ float kinv[4];
    int b = blockIdx.x;
    int c = b >> 8;
    int x = b & 255;
    int t = threadIdx.x, wid = t >> 6, lane = t & 63;
    int nk = (c == 0) ? 4 : 3;
    if (wid < nk) {
        int k = (wid == 3) ? 9 : c*3 + wid;
        const float* rw = ws + WS_ROWS + k*256;
        float v = rw[lane] + rw[64+lane] + rw[128+lane] + rw[192+lane];
        #pragma unroll
        for (int off = 32; off; off >>= 1) v += __shfl_xor(v, off);
        if (lane == 0) kinv[wid] = 1.0f / v;
    }
    __syncthreads();
    const float* uacc = ws + WS_UACC;
    for (int rr = 0; rr < 3; ++rr) {
        int xr = x - 1 + rr;
        float outv = 0.0f;
        if (xr >= 0 && xr <= 255) {
            int idx = xr*256 + t;
            for (int kk = 0; kk < nk; ++kk) {
                int k = (kk == 3) ? 9 : c*3 + kk;
                float U = uacc[k*NPIX + idx] * kinv[kk];
                float z = (U - m_[k]) / s_[k];
                outv += h_[k] * (expf(-0.5f*z*z)*2.0f - 1.0f);
            }
        }
        Ush[rr][t] = outv;
    }
    __syncthreads();
    int y = t;
    float gyA, gxA;
    sobel_at(ws + WS_ASUM, x, y, gyA, gxA);
    float v[3][3];
    #pragma unroll
    for (int ii = -1; ii <= 1; ++ii)
        #pragma unroll
        for (int jj = -1; jj <= 1; ++jj) {
            int xx = x + ii, yy = y + jj;
            v[ii+1][jj+1] = (xx < 0 || xx > 255 || yy < 0 || yy > 255)
                            ? 0.0f : Ush[ii+1][yy];
        }
    float gy = (v[0][0] + 2.0f*v[0][1] + v[0][2]) - (v[2][0] + 2.0f*v[2][1] + v[2][2]);
    float gx = (v[0][0] + 2.0f*v[1][0] + v[2][0]) - (v[0][2] + 2.0f*v[1][2] + v[2][2]);
    float a = ws[WS_APLANE + c*NPIX + x*256 + y];
    float al = (a / 3.0f); al = al * al;
    al = fminf(fmaxf(al, 0.0f), 1.0f);
    float F0 = gy * (1.0f - al) - gyA * al;
    float F1 = gx * (1.0f - al) - gxA * al;
    float d0 = fminf(fmaxf(0.2f * F0, -4.35f), 4.35f);
    float d1 = fminf(fmaxf(0.2f * F1, -4.35f), 4.35f);
    ws[WS_MUX + c*NPIX + x*256 + y] = fminf(fmaxf((float)x + 0.5f + d0, 0.65f), 255.35f);
    ws[WS_MUY + c*NPIX + x*256 + y] = fminf(fmaxf((float)y + 0.5f + d1, 0.65f), 255.35f);
}

__global__ __launch_bounds__(256) void rt_apply_v2(const float* __restrict__ ws,
                                                   float* __restrict__ out) {
    __shared__ float sA[11*256], sX[11*256], sY[11*256];
    int b = blockIdx.x;
    int c = b >> 8;
    int x = b & 255;
    const float* ap = ws + WS_APLANE + c*NPIX;
    const float* mx = ws + WS_MUX + c*NPIX;
    const float* my = ws + WS_MUY + c*NPIX;
    int t = threadIdx.x;
    #pragma unroll
    for (int i = 0; i < 11; ++i) {
        int src = (((x - (i - 5)) & 255) << 8) + t;
        sA[i*256 + t] = ap[src];
        sX[i*256 + t] = mx[src];
        sY[i*256 + t] = my[src];
    }
    __syncthreads();
    int y = t;
    float px = (float)x + 0.5f, py = (float)y + 0.5f;
    float acc = 0.0f;
    #pragma unroll
    for (int dx = -5; dx <= 5; ++dx) {
        int rb = (dx + 5) * 256;
        for (int dy = -5; dy <= 5; ++dy) {
            int sy = (y - dy) & 255;
            float a  = sA[rb + sy];
            float ax = 1.15f - fabsf(px - sX[rb + sy]);
            float ay = 1.15f - fabsf(py - sY[rb + sy]);
            ax = fminf(fmaxf(ax, 0.0f), 1.0f);
            ay = fminf(fmaxf(ay, 0.0f), 1.0f);
            acc = fmaf(a, ax * ay, acc);
        }
    }
    out[(x*256 + y)*3 + c] = acc * (1.0f / (4.0f * 0.65f * 0.65f));
}

extern "C" void kernel_launch(void* const* d_in, const int* in_sizes, int n_in,
                              void* d_out, int out_size, void* d_ws, size_t ws_size,
                              hipStream_t stream) {
    const float* A = (const float*)d_in[0];
    const float* R = (const float*)d_in[1];
    const float* r = (const float*)d_in[2];
    const float* m = (const float*)d_in[3];
    const float* s = (const float*)d_in[4];
    const float* h = (const float*)d_in[5];
    const float* a = (const float*)d_in[6];
    const float* b = (const float*)d_in[7];
    const float* w = (const float*)d_in[8];
    float* ws  = (float*)d_ws;
    float* out = (float*)d_out;

    k_prep<<<256 + 2560, 256, 0, stream>>>(A, R, r, a, b, w, ws);
    fft_fwd_real<<<13*64, 256, 0, stream>>>(ws);
    fft_fwd_cplx<<<13*64, 256, 0, stream>>>(ws);
    ifft_mul<<<10*64, 256, 0, stream>>>(ws);
    ifft_real<<<10*64, 256, 0, stream>>>(ws);
    growth_mu<<<768, 256, 0, stream>>>(ws, m, s, h);
    rt_apply_v2<<<768, 256, 0, stream>>>(ws, out);
}

// Round 7
// 122.535 us; speedup vs baseline: 6.4215x; 1.0222x over previous
//
#include <hip/hip_runtime.h>

#define NPIX 65536

// ws layout (float offsets)
#define WS_APLANE 0                  // 3 planes
#define WS_ASUM   (3*NPIX)           // 1 plane
#define WS_KOFF   (4*NPIX)           // 10 wrapped kernel planes (dead after fft pass1)
#define WS_MUX    (4*NPIX)           // overlay (post-FFT)
#define WS_MUY    (7*NPIX)           // overlay
#define WS_UACC   (14*NPIX)          // 10 U planes (written by ifft_real unpack)
#define WS_ROWS   (24*NPIX)          // 10*256 per-row kernel sums (for kinv)
#define WS_X1RE   (25*NPIX)          // 13 planes (pass1 out; planes 0-4 reused pass3 out)
#define WS_X1IM   (38*NPIX)          // 13
#define WS_X2RE   (51*NPIX)          // 13 planes (pass2 out: the full 2D hats)
#define WS_X2IM   (64*NPIX)          // 13
#define WS_END    (77*NPIX)

// ---------------- prep: repack + build wrapped kernels ----------------
__global__ void k_prep(const float* __restrict__ A,
                       const float* __restrict__ R_, const float* __restrict__ r_,
                       const float* __restrict__ a_, const float* __restrict__ b_,
                       const float* __restrict__ w_, float* __restrict__ ws) {
    int bid = blockIdx.x;
    int t = threadIdx.x;
    if (bid < 256) {                       // repack
        int idx = bid * 256 + t;
        float a0 = A[idx*3+0], a1 = A[idx*3+1], a2 = A[idx*3+2];
        ws[WS_APLANE + idx]          = a0;
        ws[WS_APLANE + NPIX + idx]   = a1;
        ws[WS_APLANE + 2*NPIX + idx] = a2;
        ws[WS_ASUM + idx] = a0 + a1 + a2;
        return;
    }
    // build kernel planes in FFT (wrapped) layout + per-(k,row) sums
    __shared__ float red[4];
    int bk = bid - 256;
    int k = bk >> 8;
    int i = bk & 255;
    int wid = t >> 6, lane = t & 63;
    float R = R_[0];
    float denom = (R + 15.0f) * r_[k];
    int di = i - 128, dj = t - 128;
    float D  = sqrtf((float)(di*di + dj*dj));
    float Dk = D / denom;
    float v = 0.0f;
    // support cutoff: beyond Dk=3, sig<=2e-9 and ker<=exp(-8) -> v<1e-12, tail
    // contribution to sums < 1e-7 absolute (totals >= ~0.05). Skip transcendentals.
    if (Dk <= 3.0f) {
        float ker = 0.0f;
        #pragma unroll
        for (int tt = 0; tt < 3; ++tt) {
            float d = Dk - a_[k*3+tt];
            ker += b_[k*3+tt] * expf(-((d*d) / w_[k*3+tt]));
        }
        // 0.5*(tanh(-5(Dk-1))+1) == logistic(-10(Dk-1)) exactly
        float sig = 1.0f / (1.0f + expf(10.0f * (Dk - 1.0f)));
        v = sig * ker;
    }
    int iw = (i + 128) & 255;   // wrapped (fftshift of centered plane)
    int jw = (t + 128) & 255;
    ws[WS_KOFF + k*NPIX + iw*256 + jw] = v;
    // row sum: wave shuffle + one barrier
    float s = v;
    #pragma unroll
    for (int off = 32; off; off >>= 1) s += __shfl_xor(s, off);
    if (lane == 0) red[wid] = s;
    __syncthreads();
    if (t == 0) ws[WS_ROWS + k*256 + i] = red[0] + red[1] + red[2] + red[3];
}

// ---------------- FFT machinery ----------------
// 256-pt radix-2 DIT on per-wave LDS re/im arrays (input already bit-reversed).
// Intra-wave only -> no barriers (DS pipe is in-order within a wave).
__device__ __forceinline__ void fft256_core(float* __restrict__ re, float* __restrict__ im,
                                            const float* __restrict__ twr,
                                            const float* __restrict__ twi, int lane) {
    #pragma unroll
    for (int s = 1; s <= 8; ++s) {
        int h = 1 << (s - 1);
        #pragma unroll
        for (int b = 0; b < 2; ++b) {
            int idx = b*64 + lane;
            int pos = idx & (h - 1);
            int g   = idx >> (s - 1);
            int i0 = (g << s) + pos;
            int i1 = i0 + h;
            int tj = pos << (8 - s);
            float wr = twr[tj], wi = twi[tj];
            float xr = re[i1], xi = im[i1];
            float br = fmaf(xr, wr, -xi*wi);
            float bi = fmaf(xr, wi,  xi*wr);
            float ar = re[i0], ai = im[i0];
            re[i0] = ar + br; im[i0] = ai + bi;
            re[i1] = ar - br; im[i1] = ai - bi;
        }
    }
}

__device__ __forceinline__ void build_tw(float* twr, float* twi, int t, float sgn) {
    if (t < 128) {
        float ang = (float)t * 0.0245436930f;   // 2*pi/256
        twr[t] = cosf(ang);
        twi[t] = sgn * sinf(ang);               // -1 forward, +1 inverse
    }
}

// transposed float4 gather-store: thread t emits (line lb..lb+3) of freq-bin t
__device__ __forceinline__ void store_t4(float* __restrict__ dst, const float* __restrict__ buf,
                                         int off, int t, int lb) {
    float4 v;
    v.x = buf[0*512 + off + t];
    v.y = buf[1*512 + off + t];
    v.z = buf[2*512 + off + t];
    v.w = buf[3*512 + off + t];
    *(float4*)&dst[t*256 + lb] = v;
}

// pass 1: forward row-FFT of 13 REAL planes packed in pairs (7 complex FFTs),
// conjugate-symmetry unpack in LDS -> 13 separate spectra in X1 (transposed).
// Plane order: 0-2 = A0-A2, 3-12 = K0-K9. Pair p: planes (2p, 2p+1); p=6: plane 12 alone.
__global__ __launch_bounds__(256) void fft_fwd_packed(float* __restrict__ ws) {
    __shared__ float buf[4*512];
    __shared__ float twr[128], twi[128];
    int p  = blockIdx.x >> 6;
    int lb = (blockIdx.x & 63) * 4;
    int wid = threadIdx.x >> 6, lane = threadIdx.x & 63;
    int t = threadIdx.x;
    build_tw(twr, twi, t, -1.0f);
    int f = 2*p, g = 2*p + 1;
    const float* frow = ws + ((f < 3) ? (WS_APLANE + f*NPIX) : (WS_KOFF + (f-3)*NPIX))
                      + (lb + wid)*256;
    const float* grow = (g < 13)
        ? ws + ((g < 3) ? (WS_APLANE + g*NPIX) : (WS_KOFF + (g-3)*NPIX)) + (lb + wid)*256
        : nullptr;
    float* re = &buf[wid*512];
    float* im = re + 256;
    #pragma unroll
    for (int e = 0; e < 4; ++e) {
        int idx = e*64 + lane;
        int dst = __brev(idx) >> 24;
        re[dst] = frow[idx];
        im[dst] = grow ? grow[idx] : 0.0f;
    }
    __syncthreads();
    fft256_core(re, im, twr, twi, lane);
    __syncthreads();
    // unpack: F=(Z(u)+conj(Z(-u)))/2, G=(Z(u)-conj(Z(-u)))/2i
    int u2 = (256 - t) & 255;
    float4 Fre, Fim, Gre, Gim;
    float* pF[4] = {&Fre.x, &Fim.x, &Gre.x, &Gim.x};
    #pragma unroll
    for (int l = 0; l < 4; ++l) {
        float zr1 = buf[l*512 + t],  zi1 = buf[l*512 + 256 + t];
        float zr2 = buf[l*512 + u2], zi2 = buf[l*512 + 256 + u2];
        pF[0][l] = 0.5f*(zr1 + zr2);
        pF[1][l] = 0.5f*(zi1 - zi2);
        pF[2][l] = 0.5f*(zi1 + zi2);
        pF[3][l] = 0.5f*(zr2 - zr1);
    }
    *(float4*)&ws[WS_X1RE + f*NPIX + t*256 + lb] = Fre;
    *(float4*)&ws[WS_X1IM + f*NPIX + t*256 + lb] = Fim;
    if (g < 13) {
        *(float4*)&ws[WS_X1RE + g*NPIX + t*256 + lb] = Gre;
        *(float4*)&ws[WS_X1IM + g*NPIX + t*256 + lb] = Gim;
    }
}

// pass 2: forward FFT along rows of X1 (original cols) -> X2 = full 2D hats
__global__ __launch_bounds__(256) void fft_fwd_cplx(float* __restrict__ ws) {
    __shared__ float buf[4*512];
    __shared__ float twr[128], twi[128];
    int p  = blockIdx.x >> 6;
    int lb = (blockIdx.x & 63) * 4;
    int wid = threadIdx.x >> 6, lane = threadIdx.x & 63;
    int t = threadIdx.x;
    build_tw(twr, twi, t, -1.0f);
    float* re = &buf[wid*512];
    float* im = re + 256;
    const float* rr = ws + WS_X1RE + p*NPIX + (lb + wid)*256;
    const float* ri = ws + WS_X1IM + p*NPIX + (lb + wid)*256;
    #pragma unroll
    for (int e = 0; e < 4; ++e) {
        int idx = e*64 + lane;
        int dst = __brev(idx) >> 24;
        re[dst] = rr[idx];
        im[dst] = ri[idx];
    }
    __syncthreads();
    fft256_core(re, im, twr, twi, lane);
    __syncthreads();
    store_t4(ws + WS_X2RE + p*NPIX, buf, 0,   t, lb);
    store_t4(ws + WS_X2IM + p*NPIX, buf, 256, t, lb);
}

// pass 3: pair j (kernels ka=2j, kb=2j+1): Z = Ahat_ca*Khat_ka + i*(Ahat_cb*Khat_kb),
// inverse FFT -> X1 plane j (packed pair rides both inverse passes by linearity).
__global__ __launch_bounds__(256) void ifft_mul_packed(float* __restrict__ ws) {
    __shared__ float buf[4*512];
    __shared__ float twr[128], twi[128];
    int j  = blockIdx.x >> 6;
    int lb = (blockIdx.x & 63) * 4;
    int wid = threadIdx.x >> 6, lane = threadIdx.x & 63;
    int t = threadIdx.x;
    build_tw(twr, twi, t, 1.0f);
    const int C0[10] = {0,0,0,1,1,1,2,2,2,0};
    int ka = 2*j, kb = 2*j + 1;
    int ca = C0[ka], cb = C0[kb];
    int rowoff = (lb + wid)*256;
    const float* arp = ws + WS_X2RE + ca*NPIX + rowoff;
    const float* aip = ws + WS_X2IM + ca*NPIX + rowoff;
    const float* krp = ws + WS_X2RE + (3+ka)*NPIX + rowoff;
    const float* kip = ws + WS_X2IM + (3+ka)*NPIX + rowoff;
    const float* brp = ws + WS_X2RE + cb*NPIX + rowoff;
    const float* bip = ws + WS_X2IM + cb*NPIX + rowoff;
    const float* lrp = ws + WS_X2RE + (3+kb)*NPIX + rowoff;
    const float* lip = ws + WS_X2IM + (3+kb)*NPIX + rowoff;
    float* re = &buf[wid*512];
    float* im = re + 256;
    #pragma unroll
    for (int e = 0; e < 4; ++e) {
        int idx = e*64 + lane;
        int dst = __brev(idx) >> 24;
        float ar = arp[idx], ai = aip[idx];
        float kr = krp[idx], ki = kip[idx];
        float uar = ar*kr - ai*ki;
        float uai = ar*ki + ai*kr;
        float br = brp[idx], bi = bip[idx];
        float lr = lrp[idx], li = lip[idx];
        float ubr = br*lr - bi*li;
        float ubi = br*li + bi*lr;
        re[dst] = uar - ubi;       // Z = Ua + i*Ub
        im[dst] = uai + ubr;
    }
    __syncthreads();
    fft256_core(re, im, twr, twi, lane);
    __syncthreads();
    store_t4(ws + WS_X1RE + j*NPIX, buf, 0,   t, lb);
    store_t4(ws + WS_X1IM + j*NPIX, buf, 256, t, lb);
}

// pass 4: inverse FFT of 5 packed planes; re/65536 -> U_{2j}, im/65536 -> U_{2j+1}
__global__ __launch_bounds__(256) void ifft_real_packed(float* __restrict__ ws) {
    __shared__ float buf[4*512];
    __shared__ float twr[128], twi[128];
    int j  = blockIdx.x >> 6;
    int lb = (blockIdx.x & 63) * 4;
    int wid = threadIdx.x >> 6, lane = threadIdx.x & 63;
    int t = threadIdx.x;
    build_tw(twr, twi, t, 1.0f);
    float* re = &buf[wid*512];
    float* im = re + 256;
    const float* rr = ws + WS_X1RE + j*NPIX + (lb + wid)*256;
    const float* ri = ws + WS_X1IM + j*NPIX + (lb + wid)*256;
    #pragma unroll
    for (int e = 0; e < 4; ++e) {
        int idx = e*64 + lane;
        int dst = __brev(idx) >> 24;
        re[dst] = rr[idx];
        im[dst] = ri[idx];
    }
    __syncthreads();
    fft256_core(re, im, twr, twi, lane);
    __syncthreads();
    const float sc = 1.0f / 65536.0f;
    float4 va, vb;
    va.x = buf[0*512 + t] * sc;       vb.x = buf[0*512 + 256 + t] * sc;
    va.y = buf[1*512 + t] * sc;       vb.y = buf[1*512 + 256 + t] * sc;
    va.z = buf[2*512 + t] * sc;       vb.z = buf[2*512 + 256 + t] * sc;
    va.w = buf[3*512 + t] * sc;       vb.w = buf[3*512 + 256 + t] * sc;
    *(float4*)&ws[WS_UACC + (2*j)*NPIX   + t*256 + lb] = va;
    *(float4*)&ws[WS_UACC + (2*j+1)*NPIX + t*256 + lb] = vb;
}

// ---------------- post stages (unchanged, proven) ----------------
__device__ inline void sobel_at(const float* __restrict__ p, int x, int y,
                                float& gy, float& gx) {
    float v[3][3];
    #pragma unroll
    for (int ii = -1; ii <= 1; ++ii)
        #pragma unroll
        for (int jj = -1; jj <= 1; ++jj) {
            int xx = x + ii, yy = y + jj;
            v[ii+1][jj+1] = (xx < 0 || xx > 255 || yy < 0 || yy > 255)
                            ? 0.0f : p[xx*256 + yy];
        }
    gy = (v[0][0] + 2.0f*v[0][1] + v[0][2]) - (v[2][0] + 2.0f*v[2][1] + v[2][2]);
    gx = (v[0][0] + 2.0f*v[1][0] + v[2][0]) - (v[0][2] + 2.0f*v[1][2] + v[2][2]);
}

__global__ __launch_bounds__(256) void growth_mu(float* __restrict__ ws,
                                                 const float* __restrict__ m_,
                                                 const float* __restrict__ s_,
                                                 const float* __restrict__ h_) {
    __shared__ float Ush[3][256];
    __shared__ float kinv[4];
    int b = blockIdx.x;
    int c = b >> 8;
    int x = b & 255;
    int t = threadIdx.x, wid = t >> 6, lane = t & 63;
    int nk = (c == 0) ? 4 : 3;
    if (wid < nk) {
        int k = (wid == 3) ? 9 : c*3 + wid;
        const float* rw = ws + WS_ROWS + k*256;
        float v = rw[lane] + rw[64+lane] + rw[128+lane] + rw[192+lane];
        #pragma unroll
        for (int off = 32; off; off >>= 1) v += __shfl_xor(v, off);
        if (lane == 0) kinv[wid] = 1.0f / v;
    }
    __syncthreads();
    const float* uacc = ws + WS_UACC;
    for (int rr = 0; rr < 3; ++rr) {
        int xr = x - 1 + rr;
        float outv = 0.0f;
        if (xr >= 0 && xr <= 255) {
            int idx = xr*256 + t;
            for (int kk = 0; kk < nk; ++kk) {
                int k = (kk == 3) ? 9 : c*3 + kk;
                float U = uacc[k*NPIX + idx] * kinv[kk];
                float z = (U - m_[k]) / s_[k];
                outv += h_[k] * (expf(-0.5f*z*z)*2.0f - 1.0f);
            }
        }
        Ush[rr][t] = outv;
    }
    __syncthreads();
    int y = t;
    float gyA, gxA;
    sobel_at(ws + WS_ASUM, x, y, gyA, gxA);
    float v[3][3];
    #pragma unroll
    for (int ii = -1; ii <= 1; ++ii)
        #pragma unroll
        for (int jj = -1; jj <= 1; ++jj) {
            int xx = x + ii, yy = y + jj;
            v[ii+1][jj+1] = (xx < 0 || xx > 255 || yy < 0 || yy > 255)
                            ? 0.0f : Ush[ii+1][yy];
        }
    float gy = (v[0][0] + 2.0f*v[0][1] + v[0][2]) - (v[2][0] + 2.0f*v[2][1] + v[2][2]);
    float gx = (v[0][0] + 2.0f*v[1][0] + v[2][0]) - (v[0][2] + 2.0f*v[1][2] + v[2][2]);
    float a = ws[WS_APLANE + c*NPIX + x*256 + y];
    float al = (a / 3.0f); al = al * al;
    al = fminf(fmaxf(al, 0.0f), 1.0f);
    float F0 = gy * (1.0f - al) - gyA * al;
    float F1 = gx * (1.0f - al) - gxA * al;
    float d0 = fminf(fmaxf(0.2f * F0, -4.35f), 4.35f);
    float d1 = fminf(fmaxf(0.2f * F1, -4.35f), 4.35f);
    ws[WS_MUX + c*NPIX + x*256 + y] = fminf(fmaxf((float)x + 0.5f + d0, 0.65f), 255.35f);
    ws[WS_MUY + c*NPIX + x*256 + y] = fminf(fmaxf((float)y + 0.5f + d1, 0.65f), 255.35f);
}

__global__ __launch_bounds__(256) void rt_apply_v2(const float* __restrict__ ws,
                                                   float* __restrict__ out) {
    __shared__ float sA[11*256], sX[11*256], sY[11*256];
    int b = blockIdx.x;
    int c = b >> 8;
    int x = b & 255;
    const float* ap = ws + WS_APLANE + c*NPIX;
    const float* mx = ws + WS_MUX + c*NPIX;
    const float* my = ws + WS_MUY + c*NPIX;
    int t = threadIdx.x;
    #pragma unroll
    for (int i = 0; i < 11; ++i) {
        int src = (((x - (i - 5)) & 255) << 8) + t;
        sA[i*256 + t] = ap[src];
        sX[i*256 + t] = mx[src];
        sY[i*256 + t] = my[src];
    }
    __syncthreads();
    int y = t;
    float px = (float)x + 0.5f, py = (float)y + 0.5f;
    float acc = 0.0f;
    #pragma unroll
    for (int dx = -5; dx <= 5; ++dx) {
        int rb = (dx + 5) * 256;
        for (int dy = -5; dy <= 5; ++dy) {
            int sy = (y - dy) & 255;
            float a  = sA[rb + sy];
            float ax = 1.15f - fabsf(px - sX[rb + sy]);
            float ay = 1.15f - fabsf(py - sY[rb + sy]);
            ax = fminf(fmaxf(ax, 0.0f), 1.0f);
            ay = fminf(fmaxf(ay, 0.0f), 1.0f);
            acc = fmaf(a, ax * ay, acc);
        }
    }
    out[(x*256 + y)*3 + c] = acc * (1.0f / (4.0f * 0.65f * 0.65f));
}

extern "C" void kernel_launch(void* const* d_in, const int* in_sizes, int n_in,
                              void* d_out, int out_size, void* d_ws, size_t ws_size,
                              hipStream_t stream) {
    const float* A = (const float*)d_in[0];
    const float* R = (const float*)d_in[1];
    const float* r = (const float*)d_in[2];
    const float* m = (const float*)d_in[3];
    const float* s = (const float*)d_in[4];
    const float* h = (const float*)d_in[5];
    const float* a = (const float*)d_in[6];
    const float* b = (const float*)d_in[7];
    const float* w = (const float*)d_in[8];
    float* ws  = (float*)d_ws;
    float* out = (float*)d_out;

    k_prep<<<256 + 2560, 256, 0, stream>>>(A, R, r, a, b, w, ws);
    fft_fwd_packed<<<7*64, 256, 0, stream>>>(ws);
    fft_fwd_cplx<<<13*64, 256, 0, stream>>>(ws);
    ifft_mul_packed<<<5*64, 256, 0, stream>>>(ws);
    ifft_real_packed<<<5*64, 256, 0, stream>>>(ws);
    growth_mu<<<768, 256, 0, stream>>>(ws, m, s, h);
    rt_apply_v2<<<768, 256, 0, stream>>>(ws, out);
}